// Round 1
// baseline (4658.440 us; speedup 1.0000x reference)
//
#include <hip/hip_runtime.h>
#include <math.h>

// AlignmentLayer: B=4, C=2048, H=W=64 (P=4096), HID=256
// Pipeline per batch:
//   Qm = Xq^T W^T + b   (P x D)
//   Km = Xp^T W^T + b   (P x D)
//   S  = Qm Km^T        (P x P)
//   A  = softmax_rows(S)
//   Out= V A^T          (C x P), V = Xp (raw prompt features)
// Workspace: Qm (16MB) + Km (16MB) + S (64MB, one batch, reused) = 96 MB.

#define BATCH 4
#define CH    2048
#define PP    4096
#define DD    256

// ---------------- Kernel 1: channel projection (1x1 conv) ----------------
// Y[b][p][o] = sum_c X[b][c][p] * Wg[o][c] + bias[o]
// grid (PP/64, DD/64, BATCH), block 256; 64x64 tile, BK=32, 4x4 microtile.
__global__ __launch_bounds__(256) void proj_kernel(
    const float* __restrict__ X, const float* __restrict__ Wg,
    const float* __restrict__ bias, float* __restrict__ Y) {
  const int b = blockIdx.z;
  const int pBase = blockIdx.x * 64;
  const int oBase = blockIdx.y * 64;
  const int tid = threadIdx.x;
  const int tx = tid & 15;   // p dir
  const int ty = tid >> 4;   // o dir
  __shared__ __align__(16) float Xs[32][68];   // [c][p], padded row
  __shared__ __align__(16) float Ws[32][68];   // [c][o]
  float acc[4][4] = {};
  const float* Xb = X + (size_t)b * CH * PP;
  for (int c0 = 0; c0 < CH; c0 += 32) {
    // Xs: coalesced along p
#pragma unroll
    for (int i = 0; i < 8; ++i) {
      int idx = tid + i * 256;
      Xs[idx >> 6][idx & 63] =
          Xb[(size_t)(c0 + (idx >> 6)) * PP + pBase + (idx & 63)];
    }
    // Ws: coalesced along c, transposed into LDS
#pragma unroll
    for (int i = 0; i < 8; ++i) {
      int idx = tid + i * 256;
      Ws[idx & 31][idx >> 5] =
          Wg[(size_t)(oBase + (idx >> 5)) * CH + c0 + (idx & 31)];
    }
    __syncthreads();
#pragma unroll
    for (int kc = 0; kc < 32; ++kc) {
      float4 xv = *(const float4*)&Xs[kc][tx * 4];
      float4 wv = *(const float4*)&Ws[kc][ty * 4];
      float xa[4] = {xv.x, xv.y, xv.z, xv.w};
      float wa[4] = {wv.x, wv.y, wv.z, wv.w};
#pragma unroll
      for (int i = 0; i < 4; ++i)
#pragma unroll
        for (int j = 0; j < 4; ++j)
          acc[i][j] += xa[i] * wa[j];
    }
    __syncthreads();
  }
#pragma unroll
  for (int i = 0; i < 4; ++i) {
    size_t off = ((size_t)b * PP + pBase + tx * 4 + i) * DD + oBase + ty * 4;
#pragma unroll
    for (int j = 0; j < 4; ++j)
      Y[off + j] = acc[i][j] + bias[oBase + ty * 4 + j];
  }
}

// ---------------- Kernel 2: scores S = Qm Km^T (one batch) ----------------
// S[p][k] = sum_d Qm[p][d]*Km[k][d]; grid (PP/128, PP/128), block 256,
// 128x128 tile, BK=32, 8x8 microtile, k-major LDS (transpose on store).
__global__ __launch_bounds__(256) void scores_kernel(
    const float* __restrict__ Qm, const float* __restrict__ Km,
    float* __restrict__ S) {
  const int kBase = blockIdx.x * 128;
  const int pBase = blockIdx.y * 128;
  const int tid = threadIdx.x;
  const int tx = tid & 15;   // k dir
  const int ty = tid >> 4;   // p dir
  __shared__ __align__(16) float Qs[32][132];  // [d][p]
  __shared__ __align__(16) float Ks[32][132];  // [d][k]
  float acc[8][8] = {};
  for (int d0 = 0; d0 < DD; d0 += 32) {
#pragma unroll
    for (int i = 0; i < 4; ++i) {
      int e = tid + i * 256;        // float4 units, 1024 total per operand
      int r = e >> 3;               // tile row 0..127
      int c4 = (e & 7) * 4;         // d offset 0..28
      float4 v = *(const float4*)&Qm[(size_t)(pBase + r) * DD + d0 + c4];
      Qs[c4 + 0][r] = v.x; Qs[c4 + 1][r] = v.y;
      Qs[c4 + 2][r] = v.z; Qs[c4 + 3][r] = v.w;
      float4 u = *(const float4*)&Km[(size_t)(kBase + r) * DD + d0 + c4];
      Ks[c4 + 0][r] = u.x; Ks[c4 + 1][r] = u.y;
      Ks[c4 + 2][r] = u.z; Ks[c4 + 3][r] = u.w;
    }
    __syncthreads();
#pragma unroll
    for (int dd = 0; dd < 32; ++dd) {
      float4 a0 = *(const float4*)&Qs[dd][ty * 8];
      float4 a1 = *(const float4*)&Qs[dd][ty * 8 + 4];
      float4 b0 = *(const float4*)&Ks[dd][tx * 8];
      float4 b1 = *(const float4*)&Ks[dd][tx * 8 + 4];
      float pr[8] = {a0.x, a0.y, a0.z, a0.w, a1.x, a1.y, a1.z, a1.w};
      float kr[8] = {b0.x, b0.y, b0.z, b0.w, b1.x, b1.y, b1.z, b1.w};
#pragma unroll
      for (int i = 0; i < 8; ++i)
#pragma unroll
        for (int j = 0; j < 8; ++j)
          acc[i][j] += pr[i] * kr[j];
    }
    __syncthreads();
  }
#pragma unroll
  for (int i = 0; i < 8; ++i) {
    size_t off = (size_t)(pBase + ty * 8 + i) * PP + kBase + tx * 8;
    *(float4*)&S[off]     = make_float4(acc[i][0], acc[i][1], acc[i][2], acc[i][3]);
    *(float4*)&S[off + 4] = make_float4(acc[i][4], acc[i][5], acc[i][6], acc[i][7]);
  }
}

// ---------------- Kernel 3: row softmax over 4096 keys ----------------
// grid PP blocks, 256 threads; each thread holds 16 elements in regs.
__global__ __launch_bounds__(256) void softmax_kernel(float* __restrict__ S) {
  float* row = S + (size_t)blockIdx.x * PP;
  const int tid = threadIdx.x;
  float4 v[4];
#pragma unroll
  for (int i = 0; i < 4; ++i)
    v[i] = *(const float4*)&row[(i * 256 + tid) * 4];
  float m = -1e30f;
#pragma unroll
  for (int i = 0; i < 4; ++i)
    m = fmaxf(m, fmaxf(fmaxf(v[i].x, v[i].y), fmaxf(v[i].z, v[i].w)));
#pragma unroll
  for (int off = 32; off > 0; off >>= 1)
    m = fmaxf(m, __shfl_xor(m, off));
  __shared__ float red[4];
  const int lane = tid & 63, wv = tid >> 6;
  if (lane == 0) red[wv] = m;
  __syncthreads();
  m = fmaxf(fmaxf(red[0], red[1]), fmaxf(red[2], red[3]));
  __syncthreads();
  float s = 0.f;
#pragma unroll
  for (int i = 0; i < 4; ++i) {
    v[i].x = __expf(v[i].x - m);
    v[i].y = __expf(v[i].y - m);
    v[i].z = __expf(v[i].z - m);
    v[i].w = __expf(v[i].w - m);
    s += v[i].x + v[i].y + v[i].z + v[i].w;
  }
#pragma unroll
  for (int off = 32; off > 0; off >>= 1)
    s += __shfl_xor(s, off);
  if (lane == 0) red[wv] = s;
  __syncthreads();
  s = red[0] + red[1] + red[2] + red[3];
  const float inv = 1.f / s;
#pragma unroll
  for (int i = 0; i < 4; ++i) {
    v[i].x *= inv; v[i].y *= inv; v[i].z *= inv; v[i].w *= inv;
    *(float4*)&row[(i * 256 + tid) * 4] = v[i];
  }
}

// ---------------- Kernel 4: Out = V A^T (one batch) ----------------
// Out[c][p] = sum_k V[c][k]*A[p][k]; grid (PP/128, CH/128), block 256,
// same NT template as scores, K=4096.
__global__ __launch_bounds__(256) void out_kernel(
    const float* __restrict__ V, const float* __restrict__ A,
    float* __restrict__ Out) {
  const int pBase = blockIdx.x * 128;
  const int cBase = blockIdx.y * 128;
  const int tid = threadIdx.x;
  const int tx = tid & 15;   // p dir
  const int ty = tid >> 4;   // c dir
  __shared__ __align__(16) float Vs[32][132];  // [k][c]
  __shared__ __align__(16) float As[32][132];  // [k][p]
  float acc[8][8] = {};
  for (int k0 = 0; k0 < PP; k0 += 32) {
#pragma unroll
    for (int i = 0; i < 4; ++i) {
      int e = tid + i * 256;
      int r = e >> 3;
      int c4 = (e & 7) * 4;
      float4 v = *(const float4*)&V[(size_t)(cBase + r) * PP + k0 + c4];
      Vs[c4 + 0][r] = v.x; Vs[c4 + 1][r] = v.y;
      Vs[c4 + 2][r] = v.z; Vs[c4 + 3][r] = v.w;
      float4 u = *(const float4*)&A[(size_t)(pBase + r) * PP + k0 + c4];
      As[c4 + 0][r] = u.x; As[c4 + 1][r] = u.y;
      As[c4 + 2][r] = u.z; As[c4 + 3][r] = u.w;
    }
    __syncthreads();
#pragma unroll
    for (int kk = 0; kk < 32; ++kk) {
      float4 a0 = *(const float4*)&Vs[kk][ty * 8];
      float4 a1 = *(const float4*)&Vs[kk][ty * 8 + 4];
      float4 b0 = *(const float4*)&As[kk][tx * 8];
      float4 b1 = *(const float4*)&As[kk][tx * 8 + 4];
      float vc[8] = {a0.x, a0.y, a0.z, a0.w, a1.x, a1.y, a1.z, a1.w};
      float ap[8] = {b0.x, b0.y, b0.z, b0.w, b1.x, b1.y, b1.z, b1.w};
#pragma unroll
      for (int i = 0; i < 8; ++i)
#pragma unroll
        for (int j = 0; j < 8; ++j)
          acc[i][j] += vc[i] * ap[j];
    }
    __syncthreads();
  }
#pragma unroll
  for (int i = 0; i < 8; ++i) {
    size_t off = (size_t)(cBase + ty * 8 + i) * PP + pBase + tx * 8;
    *(float4*)&Out[off]     = make_float4(acc[i][0], acc[i][1], acc[i][2], acc[i][3]);
    *(float4*)&Out[off + 4] = make_float4(acc[i][4], acc[i][5], acc[i][6], acc[i][7]);
  }
}

extern "C" void kernel_launch(void* const* d_in, const int* in_sizes, int n_in,
                              void* d_out, int out_size, void* d_ws, size_t ws_size,
                              hipStream_t stream) {
  const float* Xq   = (const float*)d_in[0];  // query_features  (B,C,H,W)
  const float* Xp   = (const float*)d_in[1];  // prompt_features (B,C,H,W)
  const float* Wg   = (const float*)d_in[2];  // (HID, C)
  const float* bias = (const float*)d_in[3];  // (HID,)
  float* out = (float*)d_out;

  // workspace layout (floats): Qm[B*P*D] | Km[B*P*D] | S[P*P] (per-batch reuse)
  float* Qm = (float*)d_ws;
  float* Km = Qm + (size_t)BATCH * PP * DD;
  float* Sb = Km + (size_t)BATCH * PP * DD;
  // requires ws_size >= (2*B*P*D + P*P)*4 = 96 MB

  dim3 pg(PP / 64, DD / 64, BATCH);
  proj_kernel<<<pg, 256, 0, stream>>>(Xq, Wg, bias, Qm);
  proj_kernel<<<pg, 256, 0, stream>>>(Xp, Wg, bias, Km);
  for (int b = 0; b < BATCH; ++b) {
    scores_kernel<<<dim3(PP / 128, PP / 128), 256, 0, stream>>>(
        Qm + (size_t)b * PP * DD, Km + (size_t)b * PP * DD, Sb);
    softmax_kernel<<<PP, 256, 0, stream>>>(Sb);
    out_kernel<<<dim3(PP / 128, CH / 128), 256, 0, stream>>>(
        Xp + (size_t)b * CH * PP, Sb, out + (size_t)b * CH * PP);
  }
}

// Round 2
// 1991.074 us; speedup vs baseline: 2.3397x; 2.3397x over previous
//
#include <hip/hip_runtime.h>
#include <math.h>

// AlignmentLayer: B=4, C=2048, H=W=64 (P=4096), HID=256
// Per batch:
//   Vbf = bf16(Xp_b)                      (C x P)   [cvt kernel]
//   Qm  = Xq_b^T W^T + b                  (P x D)   [fp32 tile GEMM]
//   Km  = Xp_b^T W^T + b                  (P x D)
//   S   = Qm Km^T                         (P x P)   [fp32 tile GEMM]
//   Abf = softmax_rows(S) -> bf16, written in place over S (lda=8192)
//   Out = Vbf Abf^T                       (C x P)   [bf16 MFMA GEMM]
// Workspace: Vbf 16MB | Qm 4MB | Km 4MB | S 64MB  = 88 MB.

#define BATCH 4
#define CH    2048
#define PP    4096
#define DD    256

typedef __bf16 bf16x8 __attribute__((ext_vector_type(8)));
typedef float  f32x4  __attribute__((ext_vector_type(4)));

__device__ __forceinline__ unsigned short f2bf(float f) {
  unsigned int u = __float_as_uint(f);
  unsigned int r = u + 0x7fffu + ((u >> 16) & 1u);   // RNE
  return (unsigned short)(r >> 16);
}

// ---------------- cvt: fp32 -> bf16 (vectorized) ----------------
__global__ __launch_bounds__(256) void cvt_bf16(
    const float* __restrict__ X, unsigned short* __restrict__ Y, int n4) {
  int i = blockIdx.x * blockDim.x + threadIdx.x;
  if (i < n4) {
    float4 v = ((const float4*)X)[i];
    ushort4 o;
    o.x = f2bf(v.x); o.y = f2bf(v.y); o.z = f2bf(v.z); o.w = f2bf(v.w);
    ((ushort4*)Y)[i] = o;
  }
}

// ---------------- Kernel 1: channel projection (fp32) ----------------
// Y[p][o] = sum_c X[c][p] * Wg[o][c] + bias[o]; grid (PP/64, DD/64)
__global__ __launch_bounds__(256) void proj_kernel(
    const float* __restrict__ X, const float* __restrict__ Wg,
    const float* __restrict__ bias, float* __restrict__ Y) {
  const int pBase = blockIdx.x * 64;
  const int oBase = blockIdx.y * 64;
  const int tid = threadIdx.x;
  const int tx = tid & 15;   // p dir
  const int ty = tid >> 4;   // o dir
  __shared__ __align__(16) float Xs[32][68];
  __shared__ __align__(16) float Ws[32][68];
  float acc[4][4] = {};
  for (int c0 = 0; c0 < CH; c0 += 32) {
#pragma unroll
    for (int i = 0; i < 8; ++i) {
      int idx = tid + i * 256;
      Xs[idx >> 6][idx & 63] =
          X[(size_t)(c0 + (idx >> 6)) * PP + pBase + (idx & 63)];
    }
#pragma unroll
    for (int i = 0; i < 8; ++i) {
      int idx = tid + i * 256;
      Ws[idx & 31][idx >> 5] =
          Wg[(size_t)(oBase + (idx >> 5)) * CH + c0 + (idx & 31)];
    }
    __syncthreads();
#pragma unroll
    for (int kc = 0; kc < 32; ++kc) {
      float4 xv = *(const float4*)&Xs[kc][tx * 4];
      float4 wv = *(const float4*)&Ws[kc][ty * 4];
      float xa[4] = {xv.x, xv.y, xv.z, xv.w};
      float wa[4] = {wv.x, wv.y, wv.z, wv.w};
#pragma unroll
      for (int i = 0; i < 4; ++i)
#pragma unroll
        for (int j = 0; j < 4; ++j)
          acc[i][j] += xa[i] * wa[j];
    }
    __syncthreads();
  }
#pragma unroll
  for (int i = 0; i < 4; ++i) {
    size_t off = ((size_t)pBase + tx * 4 + i) * DD + oBase + ty * 4;
#pragma unroll
    for (int j = 0; j < 4; ++j)
      Y[off + j] = acc[i][j] + bias[oBase + ty * 4 + j];
  }
}

// ---------------- Kernel 2: scores S = Qm Km^T (fp32) ----------------
__global__ __launch_bounds__(256) void scores_kernel(
    const float* __restrict__ Qm, const float* __restrict__ Km,
    float* __restrict__ S) {
  const int kBase = blockIdx.x * 128;
  const int pBase = blockIdx.y * 128;
  const int tid = threadIdx.x;
  const int tx = tid & 15;
  const int ty = tid >> 4;
  __shared__ __align__(16) float Qs[32][132];
  __shared__ __align__(16) float Ks[32][132];
  float acc[8][8] = {};
  for (int d0 = 0; d0 < DD; d0 += 32) {
#pragma unroll
    for (int i = 0; i < 4; ++i) {
      int e = tid + i * 256;
      int r = e >> 3;
      int c4 = (e & 7) * 4;
      float4 v = *(const float4*)&Qm[(size_t)(pBase + r) * DD + d0 + c4];
      Qs[c4 + 0][r] = v.x; Qs[c4 + 1][r] = v.y;
      Qs[c4 + 2][r] = v.z; Qs[c4 + 3][r] = v.w;
      float4 u = *(const float4*)&Km[(size_t)(kBase + r) * DD + d0 + c4];
      Ks[c4 + 0][r] = u.x; Ks[c4 + 1][r] = u.y;
      Ks[c4 + 2][r] = u.z; Ks[c4 + 3][r] = u.w;
    }
    __syncthreads();
#pragma unroll
    for (int dd = 0; dd < 32; ++dd) {
      float4 a0 = *(const float4*)&Qs[dd][ty * 8];
      float4 a1 = *(const float4*)&Qs[dd][ty * 8 + 4];
      float4 b0 = *(const float4*)&Ks[dd][tx * 8];
      float4 b1 = *(const float4*)&Ks[dd][tx * 8 + 4];
      float pr[8] = {a0.x, a0.y, a0.z, a0.w, a1.x, a1.y, a1.z, a1.w};
      float kr[8] = {b0.x, b0.y, b0.z, b0.w, b1.x, b1.y, b1.z, b1.w};
#pragma unroll
      for (int i = 0; i < 8; ++i)
#pragma unroll
        for (int j = 0; j < 8; ++j)
          acc[i][j] += pr[i] * kr[j];
    }
    __syncthreads();
  }
#pragma unroll
  for (int i = 0; i < 8; ++i) {
    size_t off = (size_t)(pBase + ty * 8 + i) * PP + kBase + tx * 8;
    *(float4*)&S[off]     = make_float4(acc[i][0], acc[i][1], acc[i][2], acc[i][3]);
    *(float4*)&S[off + 4] = make_float4(acc[i][4], acc[i][5], acc[i][6], acc[i][7]);
  }
}

// ---------------- Kernel 3: softmax rows; writes bf16 in place ----------------
// Reads fp32 row p of S; writes bf16 probabilities at (ushort*)S + p*8192.
// Safe aliasing: bf16 row p occupies first half of fp32 row p's bytes; all
// reads complete before the reduction barriers, writes happen after.
__global__ __launch_bounds__(256) void softmax_kernel(
    float* __restrict__ S, unsigned short* __restrict__ Ab) {
  const size_t p = blockIdx.x;
  float* row = S + p * PP;
  const int tid = threadIdx.x;
  float4 v[4];
#pragma unroll
  for (int i = 0; i < 4; ++i)
    v[i] = *(const float4*)&row[(i * 256 + tid) * 4];
  float m = -1e30f;
#pragma unroll
  for (int i = 0; i < 4; ++i)
    m = fmaxf(m, fmaxf(fmaxf(v[i].x, v[i].y), fmaxf(v[i].z, v[i].w)));
#pragma unroll
  for (int off = 32; off > 0; off >>= 1)
    m = fmaxf(m, __shfl_xor(m, off));
  __shared__ float red[4];
  const int lane = tid & 63, wv = tid >> 6;
  if (lane == 0) red[wv] = m;
  __syncthreads();
  m = fmaxf(fmaxf(red[0], red[1]), fmaxf(red[2], red[3]));
  __syncthreads();
  float s = 0.f;
#pragma unroll
  for (int i = 0; i < 4; ++i) {
    v[i].x = __expf(v[i].x - m);
    v[i].y = __expf(v[i].y - m);
    v[i].z = __expf(v[i].z - m);
    v[i].w = __expf(v[i].w - m);
    s += v[i].x + v[i].y + v[i].z + v[i].w;
  }
#pragma unroll
  for (int off = 32; off > 0; off >>= 1)
    s += __shfl_xor(s, off);
  if (lane == 0) red[wv] = s;
  __syncthreads();
  s = red[0] + red[1] + red[2] + red[3];
  const float inv = 1.f / s;
  unsigned short* orow = Ab + p * 8192;   // lda = 8192 bf16 elems
#pragma unroll
  for (int i = 0; i < 4; ++i) {
    ushort4 o;
    o.x = f2bf(v[i].x * inv); o.y = f2bf(v[i].y * inv);
    o.z = f2bf(v[i].z * inv); o.w = f2bf(v[i].w * inv);
    *(ushort4*)&orow[(i * 256 + tid) * 4] = o;
  }
}

// ---------------- Kernel 4: Out = V A^T, bf16 MFMA ----------------
// Out[c][p] = sum_k V[c][k]*A[p][k]. m97 recipe: 128x128 tile, BK=32,
// 4 waves x (4x4 of 16x16x32 mfma), global_load_lds width=16 staging.
__global__ __launch_bounds__(256) void out_mfma(
    const unsigned short* __restrict__ V,   // ldv = 4096
    const unsigned short* __restrict__ A,   // lda = 8192 (aliased over S)
    float* __restrict__ Out) {
  const int pBase = blockIdx.x * 128;
  const int cBase = blockIdx.y * 128;
  const int tid  = threadIdx.x;
  const int wave = tid >> 6;
  const int lane = tid & 63;

  __shared__ __align__(16) unsigned short As_[128 * 32];  // V tile [row][k]
  __shared__ __align__(16) unsigned short Bs_[128 * 32];  // A tile [row][k]

  const int wm = wave & 1;        // c dir (2 waves)
  const int wn = wave >> 1;       // p dir (2 waves)
  const int row16 = lane & 15;
  const int quad  = lane >> 4;
  const int koff  = quad * 8;

  // staging address components (wave stages rows [wave*32, wave*32+32))
  const int sRow = (lane >> 2);        // 0..15 within 16-row group
  const int sKc  = (lane & 3) * 8;     // k chunk, 8 bf16 = 16 B

  f32x4 acc[4][4];
#pragma unroll
  for (int i = 0; i < 4; ++i)
#pragma unroll
    for (int j = 0; j < 4; ++j)
      acc[i][j] = (f32x4){0.f, 0.f, 0.f, 0.f};

  for (int k0 = 0; k0 < PP; k0 += 32) {
#pragma unroll
    for (int t = 0; t < 2; ++t) {
      const int rowGrp = wave * 32 + t * 16;
      const unsigned short* gv =
          V + (size_t)(cBase + rowGrp + sRow) * PP + k0 + sKc;
      const unsigned short* ga =
          A + (size_t)(pBase + rowGrp + sRow) * 8192 + k0 + sKc;
      __builtin_amdgcn_global_load_lds(
          (const __attribute__((address_space(1))) unsigned int*)(uintptr_t)gv,
          (__attribute__((address_space(3))) unsigned int*)(uintptr_t)&As_[rowGrp * 32],
          16, 0, 0);
      __builtin_amdgcn_global_load_lds(
          (const __attribute__((address_space(1))) unsigned int*)(uintptr_t)ga,
          (__attribute__((address_space(3))) unsigned int*)(uintptr_t)&Bs_[rowGrp * 32],
          16, 0, 0);
    }
    __syncthreads();   // drains vmcnt before LDS reads

    bf16x8 af[4], bf[4];
#pragma unroll
    for (int i = 0; i < 4; ++i)
      af[i] = *(const bf16x8*)&As_[(wm * 64 + i * 16 + row16) * 32 + koff];
#pragma unroll
    for (int j = 0; j < 4; ++j)
      bf[j] = *(const bf16x8*)&Bs_[(wn * 64 + j * 16 + row16) * 32 + koff];
#pragma unroll
    for (int i = 0; i < 4; ++i)
#pragma unroll
      for (int j = 0; j < 4; ++j)
        acc[i][j] = __builtin_amdgcn_mfma_f32_16x16x32_bf16(
            af[i], bf[j], acc[i][j], 0, 0, 0);
    __syncthreads();   // protect LDS before next stage
  }

#pragma unroll
  for (int i = 0; i < 4; ++i) {
#pragma unroll
    for (int j = 0; j < 4; ++j) {
      const int pcol = pBase + wn * 64 + j * 16 + row16;
#pragma unroll
      for (int r = 0; r < 4; ++r) {
        const int crow = cBase + wm * 64 + i * 16 + quad * 4 + r;
        Out[(size_t)crow * PP + pcol] = acc[i][j][r];
      }
    }
  }
}

extern "C" void kernel_launch(void* const* d_in, const int* in_sizes, int n_in,
                              void* d_out, int out_size, void* d_ws, size_t ws_size,
                              hipStream_t stream) {
  const float* Xq   = (const float*)d_in[0];
  const float* Xp   = (const float*)d_in[1];
  const float* Wg   = (const float*)d_in[2];
  const float* bias = (const float*)d_in[3];
  float* out = (float*)d_out;

  // ws layout: Vbf 16MB | Qm 4MB | Km 4MB | S 64MB  (88 MB total)
  unsigned short* Vbf = (unsigned short*)d_ws;
  float* Qm = (float*)((char*)d_ws + (size_t)16 * 1024 * 1024);
  float* Km = Qm + (size_t)PP * DD;
  float* S  = Km + (size_t)PP * DD;

  const int n4 = CH * PP / 4;   // float4 count per batch image
  for (int b = 0; b < BATCH; ++b) {
    const float* Xqb = Xq + (size_t)b * CH * PP;
    const float* Xpb = Xp + (size_t)b * CH * PP;
    cvt_bf16<<<n4 / 256, 256, 0, stream>>>(Xpb, Vbf, n4);
    dim3 pg(PP / 64, DD / 64);
    proj_kernel<<<pg, 256, 0, stream>>>(Xqb, Wg, bias, Qm);
    proj_kernel<<<pg, 256, 0, stream>>>(Xpb, Wg, bias, Km);
    scores_kernel<<<dim3(PP / 128, PP / 128), 256, 0, stream>>>(Qm, Km, S);
    softmax_kernel<<<PP, 256, 0, stream>>>(S, (unsigned short*)S);
    out_mfma<<<dim3(PP / 128, CH / 128), 256, 0, stream>>>(
        Vbf, (unsigned short*)S, out + (size_t)b * CH * PP);
  }
}

// Round 3
// 1145.020 us; speedup vs baseline: 4.0684x; 1.7389x over previous
//
#include <hip/hip_runtime.h>
#include <math.h>

// AlignmentLayer: B=4, C=2048, H=W=64 (P=4096), HID=256
// Per batch:
//   Xt  = transpose(X) as fp16 [p][c]            (tsplit)
//   Q,K = proj via fp16 MFMA -> bf16 hi/lo pairs (proj_mfma)
//   S   = (Qh+Ql)(Kh+Kl)^T via 3-term bf16 MFMA  (scores_mfma)
//   A   = softmax rows -> bf16 in place over S
//   Out = Vbf A^T via bf16 MFMA                  (out_mfma)
// ws: Xt/Vbf alias 16MB | Wf 1MB | Qh,Ql,Kh,Kl 4x2MB | S 64MB = 89 MB

#define BATCH 4
#define CH    2048
#define PP    4096
#define DD    256

typedef __bf16    bf16x8 __attribute__((ext_vector_type(8)));
typedef _Float16  f16x8  __attribute__((ext_vector_type(8)));
typedef _Float16  f16x4  __attribute__((ext_vector_type(4)));
typedef float     f32x4  __attribute__((ext_vector_type(4)));

__device__ __forceinline__ unsigned short f2bf(float f) {
  unsigned int u = __float_as_uint(f);
  unsigned int r = u + 0x7fffu + ((u >> 16) & 1u);   // RNE
  return (unsigned short)(r >> 16);
}

#define GLL(src, dst) \
  __builtin_amdgcn_global_load_lds( \
      (const __attribute__((address_space(1))) unsigned int*)(uintptr_t)(src), \
      (__attribute__((address_space(3))) unsigned int*)(uintptr_t)(dst), 16, 0, 0)

// ---------------- prep_w: W fp32 [o][c] -> fp16 ----------------
__global__ __launch_bounds__(256) void prep_w(
    const float* __restrict__ W, _Float16* __restrict__ Wf) {
  int i = blockIdx.x * 256 + threadIdx.x;          // float4 units, 131072
  float4 v = ((const float4*)W)[i];
  f16x4 h = {(_Float16)v.x, (_Float16)v.y, (_Float16)v.z, (_Float16)v.w};
  ((f16x4*)Wf)[i] = h;
}

// ---------------- tsplit: X [c][p] fp32 -> Xt [p][c] fp16 ----------------
// grid (PP/64, CH/64), block 256; 64x64 tile via LDS.
__global__ __launch_bounds__(256) void tsplit(
    const float* __restrict__ X, _Float16* __restrict__ Xt) {
  __shared__ float Ls[64 * 65];
  const int tid = threadIdx.x;
  const int pBase = blockIdx.x * 64, cBase = blockIdx.y * 64;
#pragma unroll
  for (int i = 0; i < 4; ++i) {
    int e = tid + i * 256;               // 0..1023 float4 units
    int c = e >> 4, p4 = e & 15;
    float4 v = *(const float4*)&X[(size_t)(cBase + c) * PP + pBase + p4 * 4];
    Ls[c * 65 + p4 * 4 + 0] = v.x; Ls[c * 65 + p4 * 4 + 1] = v.y;
    Ls[c * 65 + p4 * 4 + 2] = v.z; Ls[c * 65 + p4 * 4 + 3] = v.w;
  }
  __syncthreads();
#pragma unroll
  for (int j = 0; j < 4; ++j) {
    int p = (tid >> 4) + j * 16;         // 0..63
    int c4 = (tid & 15) * 4;
    f16x4 h = {(_Float16)Ls[(c4 + 0) * 65 + p], (_Float16)Ls[(c4 + 1) * 65 + p],
               (_Float16)Ls[(c4 + 2) * 65 + p], (_Float16)Ls[(c4 + 3) * 65 + p]};
    *(f16x4*)&Xt[(size_t)(pBase + p) * CH + cBase + c4] = h;
  }
}

// ---------------- proj_mfma: Y = Xt Wf^T + b -> bf16 hi/lo ----------------
// Y[p][o] = sum_c Xt[p][c]*Wf[o][c] + bias[o]. grid (PP/64, DD/64), 256 thr.
// Tile 64x64, BK=64 (two 32-wide LDS buffers), fp16 16x16x32 MFMA.
__global__ __launch_bounds__(256) void proj_mfma(
    const _Float16* __restrict__ Xt, const _Float16* __restrict__ Wf,
    const float* __restrict__ bias,
    unsigned short* __restrict__ Yh, unsigned short* __restrict__ Yl) {
  const int pBase = blockIdx.x * 64;
  const int oBase = blockIdx.y * 64;
  const int tid  = threadIdx.x;
  const int wave = tid >> 6;
  const int lane = tid & 63;
  const int wm = wave & 1, wn = wave >> 1;
  const int row16 = lane & 15, quad = lane >> 4, koff = quad * 8;

  __shared__ __align__(16) _Float16 As0[64 * 32], As1[64 * 32];
  __shared__ __align__(16) _Float16 Bs0[64 * 32], Bs1[64 * 32];

  const int sRow = lane >> 2;            // 0..15
  const int sKc  = (lane & 3) * 8;       // fp16 elems, 16B chunks

  f32x4 acc[2][2];
#pragma unroll
  for (int i = 0; i < 2; ++i)
#pragma unroll
    for (int j = 0; j < 2; ++j) acc[i][j] = (f32x4){0.f, 0.f, 0.f, 0.f};

  for (int c0 = 0; c0 < CH; c0 += 64) {
    const int row = wave * 16 + sRow;    // wave-uniform base + lane scatter
    GLL(&Xt[(size_t)(pBase + row) * CH + c0 + sKc],      &As0[(wave * 16) * 32]);
    GLL(&Xt[(size_t)(pBase + row) * CH + c0 + 32 + sKc], &As1[(wave * 16) * 32]);
    GLL(&Wf[(size_t)(oBase + row) * CH + c0 + sKc],      &Bs0[(wave * 16) * 32]);
    GLL(&Wf[(size_t)(oBase + row) * CH + c0 + 32 + sKc], &Bs1[(wave * 16) * 32]);
    __syncthreads();
#pragma unroll
    for (int s = 0; s < 2; ++s) {
      const _Float16* Ap = s ? As1 : As0;
      const _Float16* Bp = s ? Bs1 : Bs0;
      f16x8 af[2], bf[2];
#pragma unroll
      for (int i = 0; i < 2; ++i)
        af[i] = *(const f16x8*)&Ap[(wm * 32 + i * 16 + row16) * 32 + koff];
#pragma unroll
      for (int j = 0; j < 2; ++j)
        bf[j] = *(const f16x8*)&Bp[(wn * 32 + j * 16 + row16) * 32 + koff];
#pragma unroll
      for (int i = 0; i < 2; ++i)
#pragma unroll
        for (int j = 0; j < 2; ++j)
          acc[i][j] = __builtin_amdgcn_mfma_f32_16x16x32_f16(
              af[i], bf[j], acc[i][j], 0, 0, 0);
    }
    __syncthreads();
  }

#pragma unroll
  for (int i = 0; i < 2; ++i)
#pragma unroll
    for (int j = 0; j < 2; ++j) {
      const int ocol = oBase + wn * 32 + j * 16 + row16;
      const float bv = bias[ocol];
#pragma unroll
      for (int r = 0; r < 4; ++r) {
        const int prow = pBase + wm * 32 + i * 16 + quad * 4 + r;
        float y = acc[i][j][r] + bv;
        unsigned short h = f2bf(y);
        float hf = __uint_as_float((unsigned int)h << 16);
        unsigned short l = f2bf(y - hf);
        Yh[(size_t)prow * DD + ocol] = h;
        Yl[(size_t)prow * DD + ocol] = l;
      }
    }
}

// ---------------- scores_mfma: S = (Qh+Ql)(Kh+Kl)^T, 3-term bf16 ----------------
// grid (PP/128, PP/128), 256 thr; tile 128x128, BK=32, K=256.
__global__ __launch_bounds__(256) void scores_mfma(
    const unsigned short* __restrict__ Qh, const unsigned short* __restrict__ Ql,
    const unsigned short* __restrict__ Kh, const unsigned short* __restrict__ Kl,
    float* __restrict__ S) {
  const int kBase = blockIdx.x * 128;
  const int pBase = blockIdx.y * 128;
  const int tid  = threadIdx.x;
  const int wave = tid >> 6;
  const int lane = tid & 63;
  const int wm = wave & 1, wn = wave >> 1;
  const int row16 = lane & 15, quad = lane >> 4, koff = quad * 8;

  __shared__ __align__(16) unsigned short Ah[128 * 32], Al[128 * 32];
  __shared__ __align__(16) unsigned short Bh[128 * 32], Bl[128 * 32];

  const int sRow = lane >> 2;
  const int sKc  = (lane & 3) * 8;

  f32x4 acc[4][4];
#pragma unroll
  for (int i = 0; i < 4; ++i)
#pragma unroll
    for (int j = 0; j < 4; ++j) acc[i][j] = (f32x4){0.f, 0.f, 0.f, 0.f};

  for (int d0 = 0; d0 < DD; d0 += 32) {
#pragma unroll
    for (int t = 0; t < 2; ++t) {
      const int rg = wave * 32 + t * 16;
      const int row = rg + sRow;
      GLL(&Qh[(size_t)(pBase + row) * DD + d0 + sKc], &Ah[rg * 32]);
      GLL(&Ql[(size_t)(pBase + row) * DD + d0 + sKc], &Al[rg * 32]);
      GLL(&Kh[(size_t)(kBase + row) * DD + d0 + sKc], &Bh[rg * 32]);
      GLL(&Kl[(size_t)(kBase + row) * DD + d0 + sKc], &Bl[rg * 32]);
    }
    __syncthreads();
    bf16x8 ah[4], al[4], bh[4], bl[4];
#pragma unroll
    for (int i = 0; i < 4; ++i) {
      ah[i] = *(const bf16x8*)&Ah[(wm * 64 + i * 16 + row16) * 32 + koff];
      al[i] = *(const bf16x8*)&Al[(wm * 64 + i * 16 + row16) * 32 + koff];
    }
#pragma unroll
    for (int j = 0; j < 4; ++j) {
      bh[j] = *(const bf16x8*)&Bh[(wn * 64 + j * 16 + row16) * 32 + koff];
      bl[j] = *(const bf16x8*)&Bl[(wn * 64 + j * 16 + row16) * 32 + koff];
    }
#pragma unroll
    for (int i = 0; i < 4; ++i)
#pragma unroll
      for (int j = 0; j < 4; ++j) {
        acc[i][j] = __builtin_amdgcn_mfma_f32_16x16x32_bf16(ah[i], bh[j], acc[i][j], 0, 0, 0);
        acc[i][j] = __builtin_amdgcn_mfma_f32_16x16x32_bf16(ah[i], bl[j], acc[i][j], 0, 0, 0);
        acc[i][j] = __builtin_amdgcn_mfma_f32_16x16x32_bf16(al[i], bh[j], acc[i][j], 0, 0, 0);
      }
    __syncthreads();
  }

#pragma unroll
  for (int i = 0; i < 4; ++i)
#pragma unroll
    for (int j = 0; j < 4; ++j) {
      const int kcol = kBase + wn * 64 + j * 16 + row16;
#pragma unroll
      for (int r = 0; r < 4; ++r) {
        const int prow = pBase + wm * 64 + i * 16 + quad * 4 + r;
        S[(size_t)prow * PP + kcol] = acc[i][j][r];
      }
    }
}

// ---------------- softmax rows; writes bf16 in place ----------------
__global__ __launch_bounds__(256) void softmax_kernel(
    float* __restrict__ S, unsigned short* __restrict__ Ab) {
  const size_t p = blockIdx.x;
  float* row = S + p * PP;
  const int tid = threadIdx.x;
  float4 v[4];
#pragma unroll
  for (int i = 0; i < 4; ++i)
    v[i] = *(const float4*)&row[(i * 256 + tid) * 4];
  float m = -1e30f;
#pragma unroll
  for (int i = 0; i < 4; ++i)
    m = fmaxf(m, fmaxf(fmaxf(v[i].x, v[i].y), fmaxf(v[i].z, v[i].w)));
#pragma unroll
  for (int off = 32; off > 0; off >>= 1)
    m = fmaxf(m, __shfl_xor(m, off));
  __shared__ float red[4];
  const int lane = tid & 63, wv = tid >> 6;
  if (lane == 0) red[wv] = m;
  __syncthreads();
  m = fmaxf(fmaxf(red[0], red[1]), fmaxf(red[2], red[3]));
  __syncthreads();
  float s = 0.f;
#pragma unroll
  for (int i = 0; i < 4; ++i) {
    v[i].x = __expf(v[i].x - m);
    v[i].y = __expf(v[i].y - m);
    v[i].z = __expf(v[i].z - m);
    v[i].w = __expf(v[i].w - m);
    s += v[i].x + v[i].y + v[i].z + v[i].w;
  }
#pragma unroll
  for (int off = 32; off > 0; off >>= 1)
    s += __shfl_xor(s, off);
  if (lane == 0) red[wv] = s;
  __syncthreads();
  s = red[0] + red[1] + red[2] + red[3];
  const float inv = 1.f / s;
  unsigned short* orow = Ab + p * 8192;
#pragma unroll
  for (int i = 0; i < 4; ++i) {
    ushort4 o;
    o.x = f2bf(v[i].x * inv); o.y = f2bf(v[i].y * inv);
    o.z = f2bf(v[i].z * inv); o.w = f2bf(v[i].w * inv);
    *(ushort4*)&orow[(i * 256 + tid) * 4] = o;
  }
}

// ---------------- cvt: fp32 -> bf16 ----------------
__global__ __launch_bounds__(256) void cvt_bf16(
    const float* __restrict__ X, unsigned short* __restrict__ Y, int n4) {
  int i = blockIdx.x * blockDim.x + threadIdx.x;
  if (i < n4) {
    float4 v = ((const float4*)X)[i];
    ushort4 o;
    o.x = f2bf(v.x); o.y = f2bf(v.y); o.z = f2bf(v.z); o.w = f2bf(v.w);
    ((ushort4*)Y)[i] = o;
  }
}

// ---------------- out_mfma: Out = V A^T (bf16, proven) ----------------
__global__ __launch_bounds__(256) void out_mfma(
    const unsigned short* __restrict__ V,
    const unsigned short* __restrict__ A,   // lda = 8192, aliased over S
    float* __restrict__ Out) {
  const int pBase = blockIdx.x * 128;
  const int cBase = blockIdx.y * 128;
  const int tid  = threadIdx.x;
  const int wave = tid >> 6;
  const int lane = tid & 63;
  const int wm = wave & 1, wn = wave >> 1;
  const int row16 = lane & 15, quad = lane >> 4, koff = quad * 8;

  __shared__ __align__(16) unsigned short As_[128 * 32];
  __shared__ __align__(16) unsigned short Bs_[128 * 32];

  const int sRow = lane >> 2;
  const int sKc  = (lane & 3) * 8;

  f32x4 acc[4][4];
#pragma unroll
  for (int i = 0; i < 4; ++i)
#pragma unroll
    for (int j = 0; j < 4; ++j) acc[i][j] = (f32x4){0.f, 0.f, 0.f, 0.f};

  for (int k0 = 0; k0 < PP; k0 += 32) {
#pragma unroll
    for (int t = 0; t < 2; ++t) {
      const int rg = wave * 32 + t * 16;
      const int row = rg + sRow;
      GLL(&V[(size_t)(cBase + row) * PP + k0 + sKc],  &As_[rg * 32]);
      GLL(&A[(size_t)(pBase + row) * 8192 + k0 + sKc], &Bs_[rg * 32]);
    }
    __syncthreads();
    bf16x8 af[4], bf[4];
#pragma unroll
    for (int i = 0; i < 4; ++i)
      af[i] = *(const bf16x8*)&As_[(wm * 64 + i * 16 + row16) * 32 + koff];
#pragma unroll
    for (int j = 0; j < 4; ++j)
      bf[j] = *(const bf16x8*)&Bs_[(wn * 64 + j * 16 + row16) * 32 + koff];
#pragma unroll
    for (int i = 0; i < 4; ++i)
#pragma unroll
      for (int j = 0; j < 4; ++j)
        acc[i][j] = __builtin_amdgcn_mfma_f32_16x16x32_bf16(
            af[i], bf[j], acc[i][j], 0, 0, 0);
    __syncthreads();
  }

#pragma unroll
  for (int i = 0; i < 4; ++i)
#pragma unroll
    for (int j = 0; j < 4; ++j) {
      const int pcol = pBase + wn * 64 + j * 16 + row16;
#pragma unroll
      for (int r = 0; r < 4; ++r) {
        const int crow = cBase + wm * 64 + i * 16 + quad * 4 + r;
        Out[(size_t)crow * PP + pcol] = acc[i][j][r];
      }
    }
}

extern "C" void kernel_launch(void* const* d_in, const int* in_sizes, int n_in,
                              void* d_out, int out_size, void* d_ws, size_t ws_size,
                              hipStream_t stream) {
  const float* Xq   = (const float*)d_in[0];
  const float* Xp   = (const float*)d_in[1];
  const float* Wg   = (const float*)d_in[2];
  const float* bias = (const float*)d_in[3];
  float* out = (float*)d_out;

  char* w = (char*)d_ws;
  const size_t MB = 1024 * 1024;
  _Float16* Xt      = (_Float16*)w;                 // 16 MB (aliased with Vbf)
  unsigned short* Vbf = (unsigned short*)w;         // same region
  _Float16* Wf      = (_Float16*)(w + 16 * MB);     // 1 MB
  unsigned short* Qh = (unsigned short*)(w + 17 * MB);
  unsigned short* Ql = (unsigned short*)(w + 19 * MB);
  unsigned short* Kh = (unsigned short*)(w + 21 * MB);
  unsigned short* Kl = (unsigned short*)(w + 23 * MB);
  float* S          = (float*)(w + 25 * MB);        // 64 MB -> 89 MB total

  prep_w<<<512, 256, 0, stream>>>(Wg, Wf);
  const int n4 = CH * PP / 4;
  for (int b = 0; b < BATCH; ++b) {
    const float* Xqb = Xq + (size_t)b * CH * PP;
    const float* Xpb = Xp + (size_t)b * CH * PP;
    tsplit<<<dim3(PP / 64, CH / 64), 256, 0, stream>>>(Xqb, Xt);
    proj_mfma<<<dim3(PP / 64, DD / 64), 256, 0, stream>>>(Xt, Wf, bias, Qh, Ql);
    tsplit<<<dim3(PP / 64, CH / 64), 256, 0, stream>>>(Xpb, Xt);
    proj_mfma<<<dim3(PP / 64, DD / 64), 256, 0, stream>>>(Xt, Wf, bias, Kh, Kl);
    scores_mfma<<<dim3(PP / 128, PP / 128), 256, 0, stream>>>(Qh, Ql, Kh, Kl, S);
    softmax_kernel<<<PP, 256, 0, stream>>>(S, (unsigned short*)S);
    cvt_bf16<<<n4 / 256, 256, 0, stream>>>(Xpb, Vbf, n4);
    out_mfma<<<dim3(PP / 128, CH / 128), 256, 0, stream>>>(
        Vbf, (unsigned short*)S, out + (size_t)b * CH * PP);
  }
}